// Round 6
// baseline (188.952 us; speedup 1.0000x reference)
//
#include <hip/hip_runtime.h>
#include <hip/hip_bf16.h>
#include <float.h>

// Co_Attention collapsed:
//   S[b,n,m] = u_fea[b,n]·E·i_fea[b,m] + u_fea[b,n]·a + g·i_fea[b,m] + s0
//   E = Wu^T M Wi, a = Wu^T M bi, g = bu^T M Wi, s0 = bu^T M bi
// p_u = softmax_n(max_m S), p_i = softmax_m(max_n S)
//
// Round 6: 4 blocks per batch (2-way n-split x 2-way m-split) -> LDS 72 KB
// -> 2 blocks/CU co-resident = 4 waves/SIMD for latency hiding. Partial
// row/col maxes in static __device__ arrays; epilogue kernel does softmaxes.
// MFMA chains split depth 6 -> 3+3 for ILP. Same tau-permuted fragment math
// as round 5.
// ws float layout: [4096..4159]=a, [4160..4223]=g, [4224]=s0,
//   ushort frags at ws+4352: EhiT[4096], EloT[4096]
//   scratch: T at [8448,12544), tb at [12544,12608)

#define NBATCH 256
#define NSEQ   512
#define DIM    64

typedef __attribute__((ext_vector_type(8))) short short8;
typedef __attribute__((ext_vector_type(4))) float f32x4;

#define MFMA16(a,b,c) __builtin_amdgcn_mfma_f32_16x16x32_bf16(a,b,c,0,0,0)

// partial maxes: g_rmax[b][mh][n], g_cmax[b][nh][m] — every slot rewritten
// each launch (no init needed); cross-kernel visibility via stream order.
__device__ float g_rmax[NBATCH*2*NSEQ];
__device__ float g_cmax[NBATCH*2*NSEQ];

union BF2 { __hip_bfloat162 b; short2 s; };

__device__ __forceinline__ void cvt2(float f, unsigned short &h, unsigned short &l) {
    unsigned u = __float_as_uint(f);
    unsigned hb = (u + 0x7FFFu + ((u >> 16) & 1u)) >> 16;
    h = (unsigned short)hb;
    float r = f - __uint_as_float(hb << 16);
    unsigned u2 = __float_as_uint(r);
    l = (unsigned short)((u2 + 0x7FFFu + ((u2 >> 16) & 1u)) >> 16);
}

__device__ __forceinline__ void cvt8(const f32x4 a, const f32x4 b, short8 &hi, short8 &lo) {
    BF2 h0, h1, h2, h3;
    h0.b = __float22bfloat162_rn(make_float2(a[0], a[1]));
    h1.b = __float22bfloat162_rn(make_float2(a[2], a[3]));
    h2.b = __float22bfloat162_rn(make_float2(b[0], b[1]));
    h3.b = __float22bfloat162_rn(make_float2(b[2], b[3]));
    hi = short8{h0.s.x, h0.s.y, h1.s.x, h1.s.y, h2.s.x, h2.s.y, h3.s.x, h3.s.y};
    BF2 l0, l1, l2, l3;
    l0.b = __float22bfloat162_rn(make_float2(a[0] - __bfloat162float(h0.b.x),
                                             a[1] - __bfloat162float(h0.b.y)));
    l1.b = __float22bfloat162_rn(make_float2(a[2] - __bfloat162float(h1.b.x),
                                             a[3] - __bfloat162float(h1.b.y)));
    l2.b = __float22bfloat162_rn(make_float2(b[0] - __bfloat162float(h2.b.x),
                                             b[1] - __bfloat162float(h2.b.y)));
    l3.b = __float22bfloat162_rn(make_float2(b[2] - __bfloat162float(h3.b.x),
                                             b[3] - __bfloat162float(h3.b.y)));
    lo = short8{l0.s.x, l0.s.y, l1.s.x, l1.s.y, l2.s.x, l2.s.y, l3.s.x, l3.s.y};
}

// ---- prep1: block d computes T[d,:] = M[d,:]@Wi and tb[d] = M[d,:]·bi ----
__global__ __launch_bounds__(64) void coatt_prep1(
    const float* __restrict__ M, const float* __restrict__ Wi,
    const float* __restrict__ bi, float* __restrict__ ws)
{
    __shared__ float Ml[64];
    const int d = blockIdx.x, f = threadIdx.x;
    Ml[f] = M[d*64 + f];
    __syncthreads();
    float s = 0.f;
    #pragma unroll 8
    for (int e = 0; e < 64; ++e) s = fmaf(Ml[e], Wi[e*64 + f], s);
    ws[8448 + d*64 + f] = s;
    float p = Ml[f] * bi[f];
    #pragma unroll
    for (int off = 1; off < 64; off <<= 1) p += __shfl_xor(p, off, 64);
    if (f == 0) ws[12544 + d] = p;
}

// ---- prep2: block c computes E[c,:] (frag-packed hi/lo), a[c]; block 0 also g, s0 ----
__global__ __launch_bounds__(64) void coatt_prep2(
    const float* __restrict__ Wu, const float* __restrict__ bu,
    float* __restrict__ ws)
{
    __shared__ float col[64];
    const int c = blockIdx.x, f = threadIdx.x;
    const float* T = ws + 8448;
    col[f] = Wu[f*64 + c];          // Wu[d=f][c]
    __syncthreads();
    float s = 0.f;
    #pragma unroll 8
    for (int d = 0; d < 64; ++d) s = fmaf(col[d], T[d*64 + f], s);
    unsigned short* efh = (unsigned short*)(ws + 4352);
    unsigned short* efl = efh + 4096;
    unsigned short h, l;
    cvt2(s, h, l);
    const int ko = c >> 5, quad = (c >> 3) & 3, j = c & 7;
    const int ft = f >> 4, f15 = f & 15;
    const int p = ft*1024 + ko*512 + (quad*16 + f15)*8 + j;
    efh[p] = h; efl[p] = l;
    float pa = col[f] * ws[12544 + f];
    #pragma unroll
    for (int off = 1; off < 64; off <<= 1) pa += __shfl_xor(pa, off, 64);
    if (f == 0) ws[4096 + c] = pa;
    if (c == 0) {
        float sg = 0.f;
        #pragma unroll 8
        for (int d = 0; d < 64; ++d) sg = fmaf(bu[d], T[d*64 + f], sg);
        ws[4160 + f] = sg;
        float ps = bu[f] * ws[12544 + f];
        #pragma unroll
        for (int off = 1; off < 64; off <<= 1) ps += __shfl_xor(ps, off, 64);
        if (f == 0) ws[4224] = ps;
    }
}

// LDS (dynamic, bytes): [0,32768) YH half; [32768,65536) YL half;
//                       [65536,73728) colp 8 x 256 f32
#define LDS_BYTES 73728

// grid 1024: bid = b*4 + nh*2 + mh
__global__ __launch_bounds__(512, 4) void coatt_main(
    const float* __restrict__ u_fea, const float* __restrict__ i_fea,
    const float* __restrict__ ws)
{
    extern __shared__ char sm[];
    unsigned short* YH = (unsigned short*)sm;
    unsigned short* YL = (unsigned short*)(sm + 32768);
    float* colp = (float*)(sm + 65536);

    const int t    = threadIdx.x;
    const int lane = t & 63, w = t >> 6, quad = lane >> 4, l15 = lane & 15;
    const int bid = blockIdx.x;
    const int b = bid >> 2, nh = (bid >> 1) & 1, mh = bid & 1;
    const float* ub = u_fea + (size_t)b * NSEQ * DIM;
    const float* ib = i_fea + (size_t)b * NSEQ * DIM;

    // ---- Y global loads first (longest latency) ----
    f32x4 ya[4], yb[4];
    #pragma unroll
    for (int q = 0; q < 4; ++q) {
        const int tloc = w*2 + (q >> 1), p = q & 1;
        const float* yp = ib + (size_t)(mh*256 + tloc*16 + l15)*DIM + p*16 + quad*4;
        ya[q] = *(const f32x4*)yp;
        yb[q] = *(const f32x4*)(yp + 32);
    }
    // ---- U global loads (wave w owns 32 n-rows) ----
    const int nbase = nh*256 + w*32;
    f32x4 u[2][4];
    #pragma unroll
    for (int g = 0; g < 2; ++g) {
        const float* up = ub + (size_t)(nbase + g*16 + l15)*DIM + quad*8;
        u[g][0] = *(const f32x4*)up;
        u[g][1] = *(const f32x4*)(up + 4);
        u[g][2] = *(const f32x4*)(up + 32);
        u[g][3] = *(const f32x4*)(up + 36);
    }
    // ---- Y cvt + frag-packed LDS store (tau layout) ----
    #pragma unroll
    for (int q = 0; q < 4; ++q) {
        const int tloc = w*2 + (q >> 1), p = q & 1;
        short8 sh, sl;
        cvt8(ya[q], yb[q], sh, sl);
        const int off = tloc*1024 + p*512 + lane*8;
        *(short8*)(YH + off) = sh;
        *(short8*)(YL + off) = sl;
    }
    // ---- r[n] + U frags ----
    const f32x4 av0 = *(const f32x4*)(ws + 4096 + quad*8);
    const f32x4 av1 = *(const f32x4*)(ws + 4096 + quad*8 + 4);
    const f32x4 av2 = *(const f32x4*)(ws + 4096 + 32 + quad*8);
    const f32x4 av3 = *(const f32x4*)(ws + 4096 + 32 + quad*8 + 4);
    const float s0 = ws[4224];
    short8 UH[2][2], UL[2][2];
    f32x4 rv[2];
    #pragma unroll
    for (int g = 0; g < 2; ++g) {
        float rp = 0.f;
        #pragma unroll
        for (int e = 0; e < 4; ++e) rp = fmaf(u[g][0][e], av0[e], rp);
        #pragma unroll
        for (int e = 0; e < 4; ++e) rp = fmaf(u[g][1][e], av1[e], rp);
        #pragma unroll
        for (int e = 0; e < 4; ++e) rp = fmaf(u[g][2][e], av2[e], rp);
        #pragma unroll
        for (int e = 0; e < 4; ++e) rp = fmaf(u[g][3][e], av3[e], rp);
        rp += __shfl_xor(rp, 16, 64);
        rp += __shfl_xor(rp, 32, 64);
        rp += s0;
        cvt8(u[g][0], u[g][1], UH[g][0], UL[g][0]);
        cvt8(u[g][2], u[g][3], UH[g][1], UL[g][1]);
        #pragma unroll
        for (int rg = 0; rg < 4; ++rg)
            rv[g][rg] = __shfl(rp, quad*4 + rg, 64);
    }
    // ---- X-gen (transpose-free, ft-pairs {p, p+2} to bound reg peak) ----
    const unsigned short* efh = (const unsigned short*)(ws + 4352);
    const unsigned short* efl = efh + 4096;
    short8 XH[2][2], XL[2][2];
    #pragma unroll
    for (int p = 0; p < 2; ++p) {
        f32x4 ct[2][2];
        #pragma unroll
        for (int fh = 0; fh < 2; ++fh) {
            const int ft = p + fh*2;
            const short8 Eh0 = *(const short8*)(efh + (ft*2+0)*512 + lane*8);
            const short8 Eh1 = *(const short8*)(efh + (ft*2+1)*512 + lane*8);
            const short8 El0 = *(const short8*)(efl + (ft*2+0)*512 + lane*8);
            const short8 El1 = *(const short8*)(efl + (ft*2+1)*512 + lane*8);
            const f32x4 gq = *(const f32x4*)(ws + 4160 + ft*16 + quad*4);
            #pragma unroll
            for (int g = 0; g < 2; ++g) {
                f32x4 cA = gq;
                cA = MFMA16(Eh0, UH[g][0], cA);
                cA = MFMA16(Eh1, UH[g][1], cA);
                cA = MFMA16(Eh0, UL[g][0], cA);
                f32x4 cB = {0.f, 0.f, 0.f, 0.f};
                cB = MFMA16(Eh1, UL[g][1], cB);
                cB = MFMA16(El0, UH[g][0], cB);
                cB = MFMA16(El1, UH[g][1], cB);
                ct[g][fh] = cA + cB;
            }
        }
        #pragma unroll
        for (int g = 0; g < 2; ++g)
            cvt8(ct[g][0], ct[g][1], XH[g][p], XL[g][p]);
    }
    __syncthreads();   // Y visible to all waves

    // ---- S-loop over 16 m-tiles (this block's m-half) ----
    f32x4 rm[2];
    rm[0] = (f32x4){-FLT_MAX, -FLT_MAX, -FLT_MAX, -FLT_MAX};
    rm[1] = rm[0];
    for (int T = 0; T < 16; ++T) {
        const unsigned short* yh2 = YH + T*1024 + lane*8;
        const unsigned short* yl2 = YL + T*1024 + lane*8;
        const short8 BH0 = *(const short8*)(yh2);
        const short8 BH1 = *(const short8*)(yh2 + 512);
        const short8 BL0 = *(const short8*)(yl2);
        const short8 BL1 = *(const short8*)(yl2 + 512);
        float cg[2];
        #pragma unroll
        for (int g = 0; g < 2; ++g) {
            f32x4 cA = rv[g];              // +r[n] folded into C-init
            cA = MFMA16(XH[g][0], BH0, cA);
            cA = MFMA16(XH[g][1], BH1, cA);
            cA = MFMA16(XH[g][0], BL0, cA);
            f32x4 cB = {0.f, 0.f, 0.f, 0.f};
            cB = MFMA16(XH[g][1], BL1, cB);
            cB = MFMA16(XL[g][0], BH0, cB);
            cB = MFMA16(XL[g][1], BH1, cB);
            const f32x4 c = cA + cB;
            rm[g][0] = fmaxf(rm[g][0], c[0]);
            rm[g][1] = fmaxf(rm[g][1], c[1]);
            rm[g][2] = fmaxf(rm[g][2], c[2]);
            rm[g][3] = fmaxf(rm[g][3], c[3]);
            cg[g] = fmaxf(fmaxf(c[0], c[1]), fmaxf(c[2], c[3]));
        }
        float cm = fmaxf(cg[0], cg[1]);
        cm = fmaxf(cm, __shfl_xor(cm, 16, 64));
        cm = fmaxf(cm, __shfl_xor(cm, 32, 64));
        if (lane < 16) colp[w*256 + T*16 + lane] = cm;
    }
    // ---- partial row-max -> global ----
    #pragma unroll
    for (int g = 0; g < 2; ++g)
        #pragma unroll
        for (int rg = 0; rg < 4; ++rg) {
            float v = rm[g][rg];
            v = fmaxf(v, __shfl_xor(v, 1, 64));
            v = fmaxf(v, __shfl_xor(v, 2, 64));
            v = fmaxf(v, __shfl_xor(v, 4, 64));
            v = fmaxf(v, __shfl_xor(v, 8, 64));
            if (l15 == 0)
                g_rmax[(size_t)(b*2 + mh)*NSEQ + nbase + g*16 + quad*4 + rg] = v;
        }
    __syncthreads();
    // ---- partial col-max (full over this block's n-rows) -> global ----
    if (t < 256) {
        float v = colp[t];
        #pragma unroll
        for (int s8 = 1; s8 < 8; ++s8) v = fmaxf(v, colp[s8*256 + t]);
        g_cmax[(size_t)(b*2 + nh)*NSEQ + mh*256 + t] = v;
    }
}

// ---- epilogue: per-batch softmaxes from partial maxes ----
__global__ __launch_bounds__(512) void coatt_epi(float* __restrict__ out)
{
    __shared__ float red[16];
    const int b = blockIdx.x, t = threadIdx.x, lane = t & 63, w = t >> 6;
    // p_u
    {
        const float v = fmaxf(g_rmax[(size_t)(b*2+0)*NSEQ + t],
                              g_rmax[(size_t)(b*2+1)*NSEQ + t]);
        float m = v;
        #pragma unroll
        for (int off = 1; off < 64; off <<= 1) m = fmaxf(m, __shfl_xor(m, off, 64));
        if (lane == 0) red[w] = m;
        __syncthreads();
        m = red[0];
        #pragma unroll
        for (int q = 1; q < 8; ++q) m = fmaxf(m, red[q]);
        const float e = __expf(v - m);
        float s = e;
        #pragma unroll
        for (int off = 1; off < 64; off <<= 1) s += __shfl_xor(s, off, 64);
        if (lane == 0) red[8+w] = s;
        __syncthreads();
        float sum = red[8];
        #pragma unroll
        for (int q = 1; q < 8; ++q) sum += red[8+q];
        out[(size_t)b*NSEQ + t] = e * (1.0f / sum);
    }
    __syncthreads();
    // p_i
    {
        const float v = fmaxf(g_cmax[(size_t)(b*2+0)*NSEQ + t],
                              g_cmax[(size_t)(b*2+1)*NSEQ + t]);
        float m = v;
        #pragma unroll
        for (int off = 1; off < 64; off <<= 1) m = fmaxf(m, __shfl_xor(m, off, 64));
        if (lane == 0) red[w] = m;
        __syncthreads();
        m = red[0];
        #pragma unroll
        for (int q = 1; q < 8; ++q) m = fmaxf(m, red[q]);
        const float e = __expf(v - m);
        float s = e;
        #pragma unroll
        for (int off = 1; off < 64; off <<= 1) s += __shfl_xor(s, off, 64);
        if (lane == 0) red[8+w] = s;
        __syncthreads();
        float sum = red[8];
        #pragma unroll
        for (int q = 1; q < 8; ++q) sum += red[8+q];
        out[(size_t)NBATCH*NSEQ + (size_t)b*NSEQ + t] = e * (1.0f / sum);
    }
}

extern "C" void kernel_launch(void* const* d_in, const int* in_sizes, int n_in,
                              void* d_out, int out_size, void* d_ws, size_t ws_size,
                              hipStream_t stream) {
    const float* u_fea = (const float*)d_in[0];
    const float* i_fea = (const float*)d_in[1];
    const float* M     = (const float*)d_in[2];
    const float* Wu    = (const float*)d_in[3];
    const float* bu    = (const float*)d_in[4];
    const float* Wi    = (const float*)d_in[5];
    const float* bi    = (const float*)d_in[6];
    float* out = (float*)d_out;
    float* ws  = (float*)d_ws;

    coatt_prep1<<<64, 64, 0, stream>>>(M, Wi, bi, ws);
    coatt_prep2<<<64, 64, 0, stream>>>(Wu, bu, ws);
    coatt_main<<<NBATCH*4, 512, LDS_BYTES, stream>>>(u_fea, i_fea, ws);
    coatt_epi<<<NBATCH, 512, 0, stream>>>(out);
}

// Round 7
// 157.767 us; speedup vs baseline: 1.1977x; 1.1977x over previous
//
#include <hip/hip_runtime.h>
#include <hip/hip_bf16.h>
#include <float.h>

// Co_Attention collapsed:
//   S[b,n,m] = u_fea[b,n]·E·i_fea[b,m] + u_fea[b,n]·a + g·i_fea[b,m] + s0
//   E = Wu^T M Wi, a = Wu^T M bi, g = bu^T M Wi, s0 = bu^T M bi
// p_u = softmax_n(max_m S), p_i = softmax_m(max_n S)
//
// Round 7: R6 structure (4 blocks/batch, 2-blocks/CU co-residency) with the
// spill bug fixed: __launch_bounds__(512,2) — empirically the 2nd arg acts as
// min BLOCKS/CU on this toolchain (R6's (512,4) forced VGPR=64 + 137 MB of
// scratch spills). Plus XCD-aware swizzle so a batch's 4 sub-blocks share one
// XCD's L2 (the split's duplicate u/i reads become L2 hits).
// ws float layout: [4096..4159]=a, [4160..4223]=g, [4224]=s0,
//   ushort frags at ws+4352: EhiT[4096], EloT[4096]
//   scratch: T at [8448,12544), tb at [12544,12608)

#define NBATCH 256
#define NSEQ   512
#define DIM    64

typedef __attribute__((ext_vector_type(8))) short short8;
typedef __attribute__((ext_vector_type(4))) float f32x4;

#define MFMA16(a,b,c) __builtin_amdgcn_mfma_f32_16x16x32_bf16(a,b,c,0,0,0)

// partial maxes: g_rmax[b][mh][n], g_cmax[b][nh][m] — every slot rewritten
// each launch (no init needed); cross-kernel visibility via stream order.
__device__ float g_rmax[NBATCH*2*NSEQ];
__device__ float g_cmax[NBATCH*2*NSEQ];

union BF2 { __hip_bfloat162 b; short2 s; };

__device__ __forceinline__ void cvt2(float f, unsigned short &h, unsigned short &l) {
    unsigned u = __float_as_uint(f);
    unsigned hb = (u + 0x7FFFu + ((u >> 16) & 1u)) >> 16;
    h = (unsigned short)hb;
    float r = f - __uint_as_float(hb << 16);
    unsigned u2 = __float_as_uint(r);
    l = (unsigned short)((u2 + 0x7FFFu + ((u2 >> 16) & 1u)) >> 16);
}

__device__ __forceinline__ void cvt8(const f32x4 a, const f32x4 b, short8 &hi, short8 &lo) {
    BF2 h0, h1, h2, h3;
    h0.b = __float22bfloat162_rn(make_float2(a[0], a[1]));
    h1.b = __float22bfloat162_rn(make_float2(a[2], a[3]));
    h2.b = __float22bfloat162_rn(make_float2(b[0], b[1]));
    h3.b = __float22bfloat162_rn(make_float2(b[2], b[3]));
    hi = short8{h0.s.x, h0.s.y, h1.s.x, h1.s.y, h2.s.x, h2.s.y, h3.s.x, h3.s.y};
    BF2 l0, l1, l2, l3;
    l0.b = __float22bfloat162_rn(make_float2(a[0] - __bfloat162float(h0.b.x),
                                             a[1] - __bfloat162float(h0.b.y)));
    l1.b = __float22bfloat162_rn(make_float2(a[2] - __bfloat162float(h1.b.x),
                                             a[3] - __bfloat162float(h1.b.y)));
    l2.b = __float22bfloat162_rn(make_float2(b[0] - __bfloat162float(h2.b.x),
                                             b[1] - __bfloat162float(h2.b.y)));
    l3.b = __float22bfloat162_rn(make_float2(b[2] - __bfloat162float(h3.b.x),
                                             b[3] - __bfloat162float(h3.b.y)));
    lo = short8{l0.s.x, l0.s.y, l1.s.x, l1.s.y, l2.s.x, l2.s.y, l3.s.x, l3.s.y};
}

// ---- prep1: block d computes T[d,:] = M[d,:]@Wi and tb[d] = M[d,:]·bi ----
__global__ __launch_bounds__(64) void coatt_prep1(
    const float* __restrict__ M, const float* __restrict__ Wi,
    const float* __restrict__ bi, float* __restrict__ ws)
{
    __shared__ float Ml[64];
    const int d = blockIdx.x, f = threadIdx.x;
    Ml[f] = M[d*64 + f];
    __syncthreads();
    float s = 0.f;
    #pragma unroll 8
    for (int e = 0; e < 64; ++e) s = fmaf(Ml[e], Wi[e*64 + f], s);
    ws[8448 + d*64 + f] = s;
    float p = Ml[f] * bi[f];
    #pragma unroll
    for (int off = 1; off < 64; off <<= 1) p += __shfl_xor(p, off, 64);
    if (f == 0) ws[12544 + d] = p;
}

// ---- prep2: block c computes E[c,:] (frag-packed hi/lo), a[c]; block 0 also g, s0 ----
__global__ __launch_bounds__(64) void coatt_prep2(
    const float* __restrict__ Wu, const float* __restrict__ bu,
    float* __restrict__ ws)
{
    __shared__ float col[64];
    const int c = blockIdx.x, f = threadIdx.x;
    const float* T = ws + 8448;
    col[f] = Wu[f*64 + c];          // Wu[d=f][c]
    __syncthreads();
    float s = 0.f;
    #pragma unroll 8
    for (int d = 0; d < 64; ++d) s = fmaf(col[d], T[d*64 + f], s);
    unsigned short* efh = (unsigned short*)(ws + 4352);
    unsigned short* efl = efh + 4096;
    unsigned short h, l;
    cvt2(s, h, l);
    const int ko = c >> 5, quad = (c >> 3) & 3, j = c & 7;
    const int ft = f >> 4, f15 = f & 15;
    const int p = ft*1024 + ko*512 + (quad*16 + f15)*8 + j;
    efh[p] = h; efl[p] = l;
    float pa = col[f] * ws[12544 + f];
    #pragma unroll
    for (int off = 1; off < 64; off <<= 1) pa += __shfl_xor(pa, off, 64);
    if (f == 0) ws[4096 + c] = pa;
    if (c == 0) {
        float sg = 0.f;
        #pragma unroll 8
        for (int d = 0; d < 64; ++d) sg = fmaf(bu[d], T[d*64 + f], sg);
        ws[4160 + f] = sg;
        float ps = bu[f] * ws[12544 + f];
        #pragma unroll
        for (int off = 1; off < 64; off <<= 1) ps += __shfl_xor(ps, off, 64);
        if (f == 0) ws[4224] = ps;
    }
}

// LDS (dynamic, bytes): [0,32768) YH half; [32768,65536) YL half;
//                       [65536,73728) colp 8 x 256 f32
#define LDS_BYTES 73728

// grid 1024; XCD swizzle: raw r -> xcd = r&7 (round-robin dispatch), so give
// all 4 sub-blocks of a batch the same r&7 -> same XCD L2.
__global__ __launch_bounds__(512, 2) void coatt_main(
    const float* __restrict__ u_fea, const float* __restrict__ i_fea,
    const float* __restrict__ ws)
{
    extern __shared__ char sm[];
    unsigned short* YH = (unsigned short*)sm;
    unsigned short* YL = (unsigned short*)(sm + 32768);
    float* colp = (float*)(sm + 65536);

    const int t    = threadIdx.x;
    const int lane = t & 63, w = t >> 6, quad = lane >> 4, l15 = lane & 15;
    const int r = blockIdx.x;
    const int b   = (r & 7)*32 + ((r >> 3) >> 2);   // batch
    const int sub = (r >> 3) & 3;
    const int nh = sub >> 1, mh = sub & 1;
    const float* ub = u_fea + (size_t)b * NSEQ * DIM;
    const float* ib = i_fea + (size_t)b * NSEQ * DIM;

    // ---- Y global loads first (longest latency) ----
    f32x4 ya[4], yb[4];
    #pragma unroll
    for (int q = 0; q < 4; ++q) {
        const int tloc = w*2 + (q >> 1), p = q & 1;
        const float* yp = ib + (size_t)(mh*256 + tloc*16 + l15)*DIM + p*16 + quad*4;
        ya[q] = *(const f32x4*)yp;
        yb[q] = *(const f32x4*)(yp + 32);
    }
    // ---- U global loads (wave w owns 32 n-rows) ----
    const int nbase = nh*256 + w*32;
    f32x4 u[2][4];
    #pragma unroll
    for (int g = 0; g < 2; ++g) {
        const float* up = ub + (size_t)(nbase + g*16 + l15)*DIM + quad*8;
        u[g][0] = *(const f32x4*)up;
        u[g][1] = *(const f32x4*)(up + 4);
        u[g][2] = *(const f32x4*)(up + 32);
        u[g][3] = *(const f32x4*)(up + 36);
    }
    // ---- Y cvt + frag-packed LDS store (tau layout) ----
    #pragma unroll
    for (int q = 0; q < 4; ++q) {
        const int tloc = w*2 + (q >> 1), p = q & 1;
        short8 sh, sl;
        cvt8(ya[q], yb[q], sh, sl);
        const int off = tloc*1024 + p*512 + lane*8;
        *(short8*)(YH + off) = sh;
        *(short8*)(YL + off) = sl;
    }
    // ---- r[n] + U frags ----
    const f32x4 av0 = *(const f32x4*)(ws + 4096 + quad*8);
    const f32x4 av1 = *(const f32x4*)(ws + 4096 + quad*8 + 4);
    const f32x4 av2 = *(const f32x4*)(ws + 4096 + 32 + quad*8);
    const f32x4 av3 = *(const f32x4*)(ws + 4096 + 32 + quad*8 + 4);
    const float s0 = ws[4224];
    short8 UH[2][2], UL[2][2];
    f32x4 rv[2];
    #pragma unroll
    for (int g = 0; g < 2; ++g) {
        float rp = 0.f;
        #pragma unroll
        for (int e = 0; e < 4; ++e) rp = fmaf(u[g][0][e], av0[e], rp);
        #pragma unroll
        for (int e = 0; e < 4; ++e) rp = fmaf(u[g][1][e], av1[e], rp);
        #pragma unroll
        for (int e = 0; e < 4; ++e) rp = fmaf(u[g][2][e], av2[e], rp);
        #pragma unroll
        for (int e = 0; e < 4; ++e) rp = fmaf(u[g][3][e], av3[e], rp);
        rp += __shfl_xor(rp, 16, 64);
        rp += __shfl_xor(rp, 32, 64);
        rp += s0;
        cvt8(u[g][0], u[g][1], UH[g][0], UL[g][0]);
        cvt8(u[g][2], u[g][3], UH[g][1], UL[g][1]);
        #pragma unroll
        for (int rg = 0; rg < 4; ++rg)
            rv[g][rg] = __shfl(rp, quad*4 + rg, 64);
    }
    // ---- X-gen (transpose-free, ft-pairs {p, p+2} to bound reg peak) ----
    const unsigned short* efh = (const unsigned short*)(ws + 4352);
    const unsigned short* efl = efh + 4096;
    short8 XH[2][2], XL[2][2];
    #pragma unroll
    for (int p = 0; p < 2; ++p) {
        f32x4 ct[2][2];
        #pragma unroll
        for (int fh = 0; fh < 2; ++fh) {
            const int ft = p + fh*2;
            const short8 Eh0 = *(const short8*)(efh + (ft*2+0)*512 + lane*8);
            const short8 Eh1 = *(const short8*)(efh + (ft*2+1)*512 + lane*8);
            const short8 El0 = *(const short8*)(efl + (ft*2+0)*512 + lane*8);
            const short8 El1 = *(const short8*)(efl + (ft*2+1)*512 + lane*8);
            const f32x4 gq = *(const f32x4*)(ws + 4160 + ft*16 + quad*4);
            #pragma unroll
            for (int g = 0; g < 2; ++g) {
                f32x4 cA = gq;
                cA = MFMA16(Eh0, UH[g][0], cA);
                cA = MFMA16(Eh1, UH[g][1], cA);
                cA = MFMA16(Eh0, UL[g][0], cA);
                f32x4 cB = {0.f, 0.f, 0.f, 0.f};
                cB = MFMA16(Eh1, UL[g][1], cB);
                cB = MFMA16(El0, UH[g][0], cB);
                cB = MFMA16(El1, UH[g][1], cB);
                ct[g][fh] = cA + cB;
            }
        }
        #pragma unroll
        for (int g = 0; g < 2; ++g)
            cvt8(ct[g][0], ct[g][1], XH[g][p], XL[g][p]);
    }
    __syncthreads();   // Y visible to all waves

    // ---- S-loop over 16 m-tiles (this block's m-half) ----
    f32x4 rm[2];
    rm[0] = (f32x4){-FLT_MAX, -FLT_MAX, -FLT_MAX, -FLT_MAX};
    rm[1] = rm[0];
    for (int T = 0; T < 16; ++T) {
        const unsigned short* yh2 = YH + T*1024 + lane*8;
        const unsigned short* yl2 = YL + T*1024 + lane*8;
        const short8 BH0 = *(const short8*)(yh2);
        const short8 BH1 = *(const short8*)(yh2 + 512);
        const short8 BL0 = *(const short8*)(yl2);
        const short8 BL1 = *(const short8*)(yl2 + 512);
        float cg[2];
        #pragma unroll
        for (int g = 0; g < 2; ++g) {
            f32x4 cA = rv[g];              // +r[n] folded into C-init
            cA = MFMA16(XH[g][0], BH0, cA);
            cA = MFMA16(XH[g][1], BH1, cA);
            cA = MFMA16(XH[g][0], BL0, cA);
            f32x4 cB = {0.f, 0.f, 0.f, 0.f};
            cB = MFMA16(XH[g][1], BL1, cB);
            cB = MFMA16(XL[g][0], BH0, cB);
            cB = MFMA16(XL[g][1], BH1, cB);
            const f32x4 c = cA + cB;
            rm[g][0] = fmaxf(rm[g][0], c[0]);
            rm[g][1] = fmaxf(rm[g][1], c[1]);
            rm[g][2] = fmaxf(rm[g][2], c[2]);
            rm[g][3] = fmaxf(rm[g][3], c[3]);
            cg[g] = fmaxf(fmaxf(c[0], c[1]), fmaxf(c[2], c[3]));
        }
        float cm = fmaxf(cg[0], cg[1]);
        cm = fmaxf(cm, __shfl_xor(cm, 16, 64));
        cm = fmaxf(cm, __shfl_xor(cm, 32, 64));
        if (lane < 16) colp[w*256 + T*16 + lane] = cm;
    }
    // ---- partial row-max -> global ----
    #pragma unroll
    for (int g = 0; g < 2; ++g)
        #pragma unroll
        for (int rg = 0; rg < 4; ++rg) {
            float v = rm[g][rg];
            v = fmaxf(v, __shfl_xor(v, 1, 64));
            v = fmaxf(v, __shfl_xor(v, 2, 64));
            v = fmaxf(v, __shfl_xor(v, 4, 64));
            v = fmaxf(v, __shfl_xor(v, 8, 64));
            if (l15 == 0)
                g_rmax[(size_t)(b*2 + mh)*NSEQ + nbase + g*16 + quad*4 + rg] = v;
        }
    __syncthreads();
    // ---- partial col-max (full over this block's n-rows) -> global ----
    if (t < 256) {
        float v = colp[t];
        #pragma unroll
        for (int s8 = 1; s8 < 8; ++s8) v = fmaxf(v, colp[s8*256 + t]);
        g_cmax[(size_t)(b*2 + nh)*NSEQ + mh*256 + t] = v;
    }
}

// ---- epilogue: per-batch softmaxes from partial maxes ----
__global__ __launch_bounds__(512) void coatt_epi(float* __restrict__ out)
{
    __shared__ float red[16];
    const int b = blockIdx.x, t = threadIdx.x, lane = t & 63, w = t >> 6;
    // p_u
    {
        const float v = fmaxf(g_rmax[(size_t)(b*2+0)*NSEQ + t],
                              g_rmax[(size_t)(b*2+1)*NSEQ + t]);
        float m = v;
        #pragma unroll
        for (int off = 1; off < 64; off <<= 1) m = fmaxf(m, __shfl_xor(m, off, 64));
        if (lane == 0) red[w] = m;
        __syncthreads();
        m = red[0];
        #pragma unroll
        for (int q = 1; q < 8; ++q) m = fmaxf(m, red[q]);
        const float e = __expf(v - m);
        float s = e;
        #pragma unroll
        for (int off = 1; off < 64; off <<= 1) s += __shfl_xor(s, off, 64);
        if (lane == 0) red[8+w] = s;
        __syncthreads();
        float sum = red[8];
        #pragma unroll
        for (int q = 1; q < 8; ++q) sum += red[8+q];
        out[(size_t)b*NSEQ + t] = e * (1.0f / sum);
    }
    __syncthreads();
    // p_i
    {
        const float v = fmaxf(g_cmax[(size_t)(b*2+0)*NSEQ + t],
                              g_cmax[(size_t)(b*2+1)*NSEQ + t]);
        float m = v;
        #pragma unroll
        for (int off = 1; off < 64; off <<= 1) m = fmaxf(m, __shfl_xor(m, off, 64));
        if (lane == 0) red[w] = m;
        __syncthreads();
        m = red[0];
        #pragma unroll
        for (int q = 1; q < 8; ++q) m = fmaxf(m, red[q]);
        const float e = __expf(v - m);
        float s = e;
        #pragma unroll
        for (int off = 1; off < 64; off <<= 1) s += __shfl_xor(s, off, 64);
        if (lane == 0) red[8+w] = s;
        __syncthreads();
        float sum = red[8];
        #pragma unroll
        for (int q = 1; q < 8; ++q) sum += red[8+q];
        out[(size_t)NBATCH*NSEQ + (size_t)b*NSEQ + t] = e * (1.0f / sum);
    }
}

extern "C" void kernel_launch(void* const* d_in, const int* in_sizes, int n_in,
                              void* d_out, int out_size, void* d_ws, size_t ws_size,
                              hipStream_t stream) {
    const float* u_fea = (const float*)d_in[0];
    const float* i_fea = (const float*)d_in[1];
    const float* M     = (const float*)d_in[2];
    const float* Wu    = (const float*)d_in[3];
    const float* bu    = (const float*)d_in[4];
    const float* Wi    = (const float*)d_in[5];
    const float* bi    = (const float*)d_in[6];
    float* out = (float*)d_out;
    float* ws  = (float*)d_ws;

    coatt_prep1<<<64, 64, 0, stream>>>(M, Wi, bi, ws);
    coatt_prep2<<<64, 64, 0, stream>>>(Wu, bu, ws);
    coatt_main<<<NBATCH*4, 512, LDS_BYTES, stream>>>(u_fea, i_fea, ws);
    coatt_epi<<<NBATCH, 512, 0, stream>>>(out);
}